// Round 9
// baseline (157.428 us; speedup 1.0000x reference)
//
#include <hip/hip_runtime.h>
#include <math.h>
#include <limits.h>

#define BB 8
#define NN 50000
#define NCH 8
#define CHSZ 6250                      // NN/NCH
#define EPSF 1.1920928955078125e-07f   // float32 machine eps
#define CEPS2 1.0e-6f                  // CHAR_EPS^2
#define QS   4194304.0f                // 2^22 fixed-point quantum for packed num
#define QINV (1.0f/4194304.0f)

// ---- ws layout (float offsets; total ~3.5 MB) ----
// params: 8*32 floats = [a, invP0..3, tf_pos, tf_neg, tl_pos, tl_neg, tmax, G0..3, ...]
#define OFF_PARAMS 0
#define OFF_SUMS   256      // [0] evloss [1] smooth [2] counter (zeroed in finalize)
#define OFF_MINMAX 384      // int[8][8][4] per (batch,chunk): minp,maxp,minn,maxn
#define OFF_HIST   640      // u32[8][8][512]
#define OFF_COFF   33408    // u32[8][8][512] chunk write-offsets
#define OFF_PRE    66176    // u32[8][513] (stride 516) exclusive prefix per bin, [512]=NN
#define OFF_DG     70336    // uint2[8][50000] sorted digest {f32 tb; x|y<<8|pol<<16}

// scatter tiles (both signs per block, split LDS):
//  [0,16)   s0 (b,pol) full 32x32      (2x1024  = 16KB)
//  [16,32)  s1 (b,pol) full 64x64      (2x4096  = 64KB)
//  [32,96)  s2 (b,pol,4 bands x32row)  (2x4096  = 64KB)
//  [96,352) s3 (b,pol,16 bands x16row) (2x4096  = 64KB)
#define SC_BLOCKS 352
#define SM_BLOCKS 256
#define TOT_BLOCKS (SC_BLOCKS + SM_BLOCKS)
#define SMOOTH_N  1392640

__device__ __forceinline__ unsigned long long encq(float v) {
    return (unsigned long long)((1LL << 40) + (long long)__float2int_rn(v * QS));
}

// valid on thread 0 only
__device__ __forceinline__ float block_reduce_sum(float v) {
    __shared__ float sm_[16];
    int lane = threadIdx.x & 63, wid = threadIdx.x >> 6;
    #pragma unroll
    for (int o = 32; o > 0; o >>= 1) v += __shfl_down(v, o);
    if (lane == 0) sm_[wid] = v;
    __syncthreads();
    float r = 0.0f;
    if (threadIdx.x == 0) {
        int nw = blockDim.x >> 6;
        for (int i = 0; i < nw; ++i) r += sm_[i];
    }
    __syncthreads();
    return r;
}

// valid on thread 0 only; safe for repeated calls
__device__ __forceinline__ float block_reduce_max(float v) {
    __shared__ float smx[16];
    int lane = threadIdx.x & 63, wid = threadIdx.x >> 6;
    #pragma unroll
    for (int o = 32; o > 0; o >>= 1) v = fmaxf(v, __shfl_down(v, o));
    if (lane == 0) smx[wid] = v;
    __syncthreads();
    float r = 0.0f;
    if (threadIdx.x == 0) {
        int nw = blockDim.x >> 6;
        for (int i = 0; i < nw; ++i) r = fmaxf(r, smx[i]);
    }
    __syncthreads();
    return r;
}

// pass 1: per (batch, chunk) histogram of (pol,y) + min/max event index per polarity
__global__ __launch_bounds__(1024) void stats_kernel(const float* __restrict__ ev, float* __restrict__ ws) {
    int b = blockIdx.x >> 3, c = blockIdx.x & 7;
    const float* ey = ev + ((size_t)b * 4 + 1) * NN;
    const float* ep = ev + ((size_t)b * 4 + 3) * NN;
    __shared__ unsigned hist[512];
    __shared__ int s0[1024], s1[1024], s2[1024], s3[1024];
    for (int i = threadIdx.x; i < 512; i += 1024) hist[i] = 0;
    __syncthreads();
    int minp = INT_MAX, maxp = -1, minn = INT_MAX, maxn = -1;
    int start = c * CHSZ, end = start + CHSZ;
    for (int n = start + threadIdx.x; n < end; n += 1024) {
        int yv = (int)ey[n];
        bool pos = (ep[n] == 1.0f);
        atomicAdd(&hist[(pos ? 0 : 256) + yv], 1u);
        if (pos) { minp = min(minp, n); maxp = max(maxp, n); }
        else     { minn = min(minn, n); maxn = max(maxn, n); }
    }
    int tid = threadIdx.x;
    s0[tid] = minp; s1[tid] = maxp; s2[tid] = minn; s3[tid] = maxn;
    __syncthreads();
    for (int o = 512; o > 0; o >>= 1) {
        if (tid < o) {
            s0[tid] = min(s0[tid], s0[tid + o]);
            s1[tid] = max(s1[tid], s1[tid + o]);
            s2[tid] = min(s2[tid], s2[tid + o]);
            s3[tid] = max(s3[tid], s3[tid + o]);
        }
        __syncthreads();
    }
    unsigned* gh = (unsigned*)(ws + OFF_HIST) + ((b << 3) + c) * 512;
    for (int i = tid; i < 512; i += 1024) gh[i] = hist[i];
    if (tid == 0) {
        int* mm = (int*)(ws + OFF_MINMAX) + ((b << 3) + c) * 4;
        mm[0] = s0[0]; mm[1] = s1[0]; mm[2] = s2[0]; mm[3] = s3[0];
    }
}

// pass 2 (one block per batch): params + guards + bin prefix + chunk offsets
__global__ __launch_bounds__(1024) void finalize_kernel(const float* __restrict__ ev,
                            const float* __restrict__ f0, const float* __restrict__ f1,
                            const float* __restrict__ f2, const float* __restrict__ f3,
                            float* __restrict__ ws) {
    int b = blockIdx.x, tid = threadIdx.x;
    float* pp = ws + OFF_PARAMS + b * 32;
    __shared__ float smaxfy[4];

    // max |fy| per scale (flow planes are small; strided reduce)
    const float* fys[4] = { f0 + ((size_t)b * 2 + 1) * 1024,  f1 + ((size_t)b * 2 + 1) * 4096,
                            f2 + ((size_t)b * 2 + 1) * 16384, f3 + ((size_t)b * 2 + 1) * 65536 };
    const int fhw[4] = { 1024, 4096, 16384, 65536 };
    for (int s = 0; s < 4; ++s) {
        float m = 0.0f;
        for (int i = tid; i < fhw[s]; i += 1024) m = fmaxf(m, fabsf(fys[s][i]));
        float r = block_reduce_max(m);
        if (tid == 0) smaxfy[s] = r;
    }
    __syncthreads();

    if (tid == 0) {
        const int* mm = (const int*)(ws + OFF_MINMAX) + (b << 3) * 4;
        int mp = INT_MAX, xp = -1, mn = INT_MAX, xn = -1;
        for (int c = 0; c < 8; ++c) {
            mp = min(mp, mm[c * 4 + 0]); xp = max(xp, mm[c * 4 + 1]);
            mn = min(mn, mm[c * 4 + 2]); xn = max(xn, mm[c * 4 + 3]);
        }
        if (xp < 0) { mp = 0; xp = NN - 1; }   // argmax(all-false)==0 semantics
        if (xn < 0) { mn = 0; xn = NN - 1; }
        const float* t = ev + ((size_t)b * 4 + 2) * NN;
        float a = t[0], tlast = t[NN - 1];
        float d0 = tlast - a + EPSF;
        float P  = d0;
        float r  = (tlast - a) / d0;
        pp[0] = a;
        pp[1] = 1.0f / P;
        for (int i = 1; i < 4; ++i) {
            float d = r + EPSF;
            P *= d;
            r  = r / d;
            pp[1 + i] = 1.0f / P;
        }
        pp[5] = t[mp];   // first pos
        pp[6] = t[mn];   // first neg
        pp[7] = t[xp];   // last pos
        pp[8] = t[xn];   // last neg
        float tmax = tlast - a;
        pp[9] = tmax;
        // guard G per scale: max |t_| * max|fy|, t_ linear in tb -> extremes at tb in {0, tmax}
        for (int s = 0; s < 4; ++s) {
            float invP = pp[1 + s];
            float T = 0.0f;
            for (int pol = 0; pol < 2; ++pol) {
                float tf = pp[5 + pol] - a, tl = pp[7 + pol] - a;
                float b0 = tl * invP + EPSF;    // sgn 0
                float b1 = tf * invP - EPSF;    // sgn 1
                T = fmaxf(T, fmaxf(fabsf(b0), fabsf(b0 - tmax * invP)));
                T = fmaxf(T, fmaxf(fabsf(b1), fabsf(b1 - tmax * invP)));
            }
            pp[10 + s] = (float)((int)ceilf(T * smaxfy[s]) + 1);
        }
        if (b == 0) { ws[OFF_SUMS] = 0.0f; ws[OFF_SUMS + 1] = 0.0f; ws[OFF_SUMS + 2] = 0.0f; }
    }
    __syncthreads();

    // bin prefix (512 bins) + per-chunk offsets
    __shared__ unsigned tot[512], bincnt[512];
    if (tid < 512) {
        unsigned run = 0;
        for (int c = 0; c < 8; ++c) {
            const unsigned* gh = (const unsigned*)(ws + OFF_HIST) + ((b << 3) + c) * 512;
            unsigned* gc = (unsigned*)(ws + OFF_COFF) + ((b << 3) + c) * 512;
            gc[tid] = run;
            run += gh[tid];
        }
        bincnt[tid] = run;
        tot[tid] = run;
    }
    __syncthreads();
    for (int o = 1; o < 512; o <<= 1) {
        unsigned v = 0;
        if (tid < 512 && tid >= o) v = tot[tid - o];
        __syncthreads();
        if (tid < 512 && tid >= o) tot[tid] += v;
        __syncthreads();
    }
    if (tid < 512) {
        unsigned Pex = tot[tid] - bincnt[tid];
        unsigned* gp = (unsigned*)(ws + OFF_PRE) + b * 516;
        gp[tid] = Pex;
        if (tid == 511) gp[512] = tot[511];   // == NN
        for (int c = 0; c < 8; ++c) {
            unsigned* gc = (unsigned*)(ws + OFF_COFF) + ((b << 3) + c) * 512;
            gc[tid] += Pex;
        }
    }
}

// pass 3: write digest sorted by (pol, y)
__global__ __launch_bounds__(1024) void sortwrite_kernel(const float* __restrict__ ev, float* __restrict__ ws) {
    int b = blockIdx.x >> 3, c = blockIdx.x & 7;
    const float* ex = ev + (size_t)b * 4 * NN;
    const float* ey = ex + NN;
    const float* et = ex + 2 * NN;
    const float* ep = ex + 3 * NN;
    __shared__ unsigned cur[512];
    const unsigned* gc = (const unsigned*)(ws + OFF_COFF) + ((b << 3) + c) * 512;
    for (int i = threadIdx.x; i < 512; i += 1024) cur[i] = gc[i];
    __syncthreads();
    float a = et[0];
    uint2* dg = (uint2*)(ws + OFF_DG) + (size_t)b * NN;
    int start = c * CHSZ, end = start + CHSZ;
    for (int n = start + threadIdx.x; n < end; n += 1024) {
        float x = ex[n], y = ey[n], tt = et[n], p = ep[n];
        int yv = (int)y;
        int pol = (p == 1.0f) ? 0 : 1;
        unsigned idx = atomicAdd(&cur[(pol << 8) + yv], 1u);
        uint2 d;
        d.x = __float_as_uint(tt - a);
        d.y = (unsigned)(int)x | ((unsigned)yv << 8) | ((unsigned)pol << 16);
        dg[idx] = d;
    }
}

__device__ __forceinline__ float charb_fast(float d) {
    return __expf(0.45f * __logf(d * d + CEPS2));
}

// mega: blocks [0,352) scatter (both signs per block, split LDS, fused reduce),
// [352,608) smoothness; last block (device counter) writes the 3 outputs.
__global__ __launch_bounds__(1024) void mega_kernel(const float* __restrict__ f0,
                            const float* __restrict__ f1, const float* __restrict__ f2,
                            const float* __restrict__ f3, float* __restrict__ ws,
                            float* __restrict__ out) {
    float* sums = ws + OFF_SUMS;
    float r = 0.0f;
    int slot;
    if (blockIdx.x < SC_BLOCKS) {
        slot = 0;
        __shared__ unsigned long long lds[8192];   // 64 KB (2 sign tiles)
        int bi = blockIdx.x;
        int b, pol, scale, lo, nrows, w, sh;
        const float* fl;
        if (bi < 16)      {              b = bi & 7; pol = bi >> 3;                               scale = 0; lo = 0;                nrows = 32; w = 32;  sh = 3; fl = f0; }
        else if (bi < 32) { int g = bi - 16; b = g & 7; pol = g >> 3;                             scale = 1; lo = 0;                nrows = 64; w = 64;  sh = 2; fl = f1; }
        else if (bi < 96) { int g = bi - 32; b = g & 7; int q = g >> 3; pol = q & 1;              scale = 2; lo = (q >> 1) * 32;    nrows = 32; w = 128; sh = 1; fl = f2; }
        else              { int g = bi - 96; b = g & 7; int q = g >> 3; pol = q & 1;              scale = 3; lo = (q >> 1) * 16;    nrows = 16; w = 256; sh = 0; fl = f3; }
        int hw = w * w;
        int ncell = nrows * w;        // <= 4096
        int ntot  = 2 * ncell;

        for (int i = threadIdx.x; i < ntot / 2; i += 1024)
            ((ulonglong2*)lds)[i] = make_ulonglong2(0ULL, 0ULL);
        __syncthreads();

        const float* pp = ws + OFF_PARAMS + b * 32;
        float a    = pp[0];
        float invP = pp[1 + scale];
        float base0 = (pp[7 + pol] - a) * invP + EPSF;   // sgn 0: tl*invP + EPS
        float base1 = (pp[5 + pol] - a) * invP - EPSF;   // sgn 1: tf*invP - EPS
        fl += (size_t)b * 2 * hw;

        // scan range from sorted digest
        int ylo = 0, yhi = 255;
        if (scale >= 2) {
            int G = (int)pp[10 + scale];
            ylo = max((lo - G) << sh, 0);
            yhi = min(((lo + nrows - 1 + G) << sh) + ((1 << sh) - 1), 255);
        }
        const unsigned* gp = (const unsigned*)(ws + OFF_PRE) + b * 516 + (pol << 8);
        int r0 = (int)gp[ylo], r1 = (int)gp[yhi + 1];

        const uint2* dg = ((const uint2*)(ws + OFF_DG)) + (size_t)b * NN;
        float wm1 = (float)(w - 1);

        for (int n = r0 + threadIdx.x; n < r1; n += 1024) {
            uint2 d = dg[n];
            float tb = __uint_as_float(d.x);
            int xi = (int)(d.y & 255u) >> sh;
            int yi = (int)((d.y >> 8) & 255u) >> sh;
            float fx = fl[yi * w + xi];
            float fy = fl[hw + yi * w + xi];
            float tn = tb * invP;
            float t0s = base0 - tn;
            float t1s = base1 - tn;
            #pragma unroll
            for (int sgn = 0; sgn < 2; ++sgn) {
                float t_ = (sgn == 0) ? t0s : t1s;
                float x_ = fminf(fmaxf((float)xi + t_ * fx, 0.0f), wm1);
                float y_ = fminf(fmaxf((float)yi + t_ * fy, 0.0f), wm1);
                float x0 = floorf(x_), x1 = ceilf(x_);
                float y0 = floorf(y_), y1 = ceilf(y_);
                float x0r = 1.0f - (x_ - x0), x1r = 1.0f - (x1 - x_);
                float y0r = 1.0f - (y_ - y0), y1r = 1.0f - (y1 - y_);
                int ix0 = (int)x0, ix1 = (int)x1;
                int rr0 = (int)y0 - lo, rr1 = (int)y1 - lo;
                unsigned long long* L = lds + sgn * ncell;
                if (rr0 >= 0 && rr0 < nrows) {
                    atomicAdd(&L[rr0 * w + ix0], encq((x0r * y0r + EPSF) * t_));
                    atomicAdd(&L[rr0 * w + ix1], encq((x1r * y0r + EPSF) * t_));
                }
                if (rr1 >= 0 && rr1 < nrows) {
                    atomicAdd(&L[rr1 * w + ix0], encq((x0r * y1r + EPSF) * t_));
                    atomicAdd(&L[rr1 * w + ix1], encq((x1r * y1r + EPSF) * t_));
                }
            }
        }
        __syncthreads();

        float acc = 0.0f;
        for (int i = threadIdx.x; i < ntot; i += 1024) {
            unsigned long long A = lds[i];
            if (!A) continue;
            unsigned long long cnt = (A + (1ULL << 39)) >> 40;
            long long sq = (long long)(A - (cnt << 40));
            float num = (float)sq * QINV;
            float v = num / ((float)cnt + EPSF);
            acc += v * v;
        }
        r = block_reduce_sum(acc);
    } else {
        slot = 1;
        int bi = blockIdx.x - SC_BLOCKS;
        int stride = SM_BLOCKS * 1024;
        float acc = 0.0f;
        for (int j = bi * 1024 + threadIdx.x; j < SMOOTH_N; j += stride) {
            const float* F; int jj, lg, lw;
            if (j < 16384)       { F = f0; jj = j;          lg = 10; lw = 5; }
            else if (j < 81920)  { F = f1; jj = j - 16384;  lg = 12; lw = 6; }
            else if (j < 344064) { F = f2; jj = j - 81920;  lg = 14; lw = 7; }
            else                 { F = f3; jj = j - 344064; lg = 16; lw = 8; }
            int hw = 1 << lg;
            int w  = 1 << lw;
            int plane = jj >> lg;
            int pix   = jj & (hw - 1);
            int yy = pix >> lw;
            int xx = pix & (w - 1);
            const float* Fp = F + ((size_t)plane << lg);
            float v = Fp[pix];
            bool yok = (yy < w - 1);
            bool xok = (xx < w - 1);
            float inv_e = 0.5f / (16.0f * (float)(w - 1) * (float)w);
            float inv_d = 0.5f / (16.0f * (float)(w - 1) * (float)(w - 1));
            if (yok) { float d = Fp[pix + w] - v;          acc += charb_fast(d) * inv_e; }
            if (xok) { float d = Fp[pix + 1] - v;          acc += charb_fast(d) * inv_e; }
            if (yok && xok) {
                float d  = Fp[pix + w + 1] - v;            acc += charb_fast(d)  * inv_d;
                float d2 = Fp[pix + 1] - Fp[pix + w];      acc += charb_fast(d2) * inv_d;
            }
        }
        r = block_reduce_sum(acc);
    }
    if (threadIdx.x == 0) {
        atomicAdd(&sums[slot], r);
        __threadfence();
        unsigned old = atomicAdd((unsigned*)&sums[2], 1u);
        if (old == TOT_BLOCKS - 1) {
            float evl = atomicAdd(&sums[0], 0.0f);   // coherent reads
            float sm  = atomicAdd(&sums[1], 0.0f);
            out[0] = evl + sm;
            out[1] = evl;
            out[2] = sm;
        }
    }
}

extern "C" void kernel_launch(void* const* d_in, const int* in_sizes, int n_in,
                              void* d_out, int out_size, void* d_ws, size_t ws_size,
                              hipStream_t stream) {
    const float* ev = (const float*)d_in[0];
    const float* f0 = (const float*)d_in[1];
    const float* f1 = (const float*)d_in[2];
    const float* f2 = (const float*)d_in[3];
    const float* f3 = (const float*)d_in[4];
    float* ws  = (float*)d_ws;
    float* out = (float*)d_out;

    stats_kernel<<<64, 1024, 0, stream>>>(ev, ws);
    finalize_kernel<<<BB, 1024, 0, stream>>>(ev, f0, f1, f2, f3, ws);
    sortwrite_kernel<<<64, 1024, 0, stream>>>(ev, ws);
    mega_kernel<<<TOT_BLOCKS, 1024, 0, stream>>>(f0, f1, f2, f3, ws, out);
}